// Round 1
// baseline (1893.805 us; speedup 1.0000x reference)
//
#include <hip/hip_runtime.h>
#include <hip/hip_bf16.h>
#include <math.h>

// Problem constants
#define B_  2
#define S_  2048
#define D_  1024
#define H_  16
#define DK_ 64

// ---------------------------------------------------------------------------
// Projection GEMM: C[m,n] = sum_k A[m,k] * W[n,k] + bias[n]
//   A: [M=4096, K=1024] row-major, W: [N=1024, K=1024] row-major ("NT" gemm).
// headed=1: write out[((b*H+h)*S+s)*DK+dk]  (split-heads layout for Q/K/V)
// headed=0: write out[m*D + n]              (plain, for final projection)
// 64x64 tile, 256 threads, 4x4 acc per thread, BK=16.
// LDS padded to 17 so reads/writes are <=2-way bank aliased (free on CDNA4).
// ---------------------------------------------------------------------------
__global__ __launch_bounds__(256)
void proj_kernel(const float* __restrict__ A, const float* __restrict__ W,
                 const float* __restrict__ bias, float* __restrict__ out,
                 int headed)
{
    __shared__ float sA[64][17];
    __shared__ float sW[64][17];

    const int tid = threadIdx.x;
    const int tx = tid & 15;   // N direction (4 cols each)
    const int ty = tid >> 4;   // M direction (4 rows each)
    const int kk = tid & 15;   // load: k index within BK=16
    const int mm = tid >> 4;   // load: row group

    const int m0 = blockIdx.y * 64;
    const int n0 = blockIdx.x * 64;

    float acc[4][4] = {};

    for (int k0 = 0; k0 < D_; k0 += 16) {
#pragma unroll
        for (int i = 0; i < 4; ++i) {
            sA[mm + i * 16][kk] = A[(size_t)(m0 + mm + i * 16) * D_ + k0 + kk];
            sW[mm + i * 16][kk] = W[(size_t)(n0 + mm + i * 16) * D_ + k0 + kk];
        }
        __syncthreads();
#pragma unroll
        for (int k = 0; k < 16; ++k) {
            float a[4], w[4];
#pragma unroll
            for (int i = 0; i < 4; ++i) a[i] = sA[ty * 4 + i][k];
#pragma unroll
            for (int j = 0; j < 4; ++j) w[j] = sW[tx * 4 + j][k];
#pragma unroll
            for (int i = 0; i < 4; ++i)
#pragma unroll
                for (int j = 0; j < 4; ++j)
                    acc[i][j] += a[i] * w[j];
        }
        __syncthreads();
    }

#pragma unroll
    for (int i = 0; i < 4; ++i) {
        const int m = m0 + ty * 4 + i;
        const int b = m / S_;
        const int s = m % S_;
#pragma unroll
        for (int j = 0; j < 4; ++j) {
            const int n = n0 + tx * 4 + j;
            const float v = acc[i][j] + bias[n];
            if (headed) {
                const int h  = n / DK_;
                const int dk = n % DK_;
                out[((size_t)((b * H_ + h) * S_) + s) * DK_ + dk] = v;
            } else {
                out[(size_t)m * D_ + n] = v;
            }
        }
    }
}

// ---------------------------------------------------------------------------
// Flash-style attention: one block per (b, h, 64-row q-tile).
// Q/K/V in [B,H,S,DK] fp32. Streams K/V in 64-row tiles with online softmax.
// mask: [B,1,1,S] int32 — key-position mask (mask==0 -> score = -1e9).
// Output written straight into X [B,S,D] (transpose+merge-heads fused).
// ---------------------------------------------------------------------------
__global__ __launch_bounds__(256)
void attn_kernel(const float* __restrict__ Q, const float* __restrict__ K,
                 const float* __restrict__ V, const int* __restrict__ mask,
                 float* __restrict__ X)
{
    const int qt = blockIdx.x % (S_ / 64);
    const int bh = blockIdx.x / (S_ / 64);
    const int b  = bh / H_;
    const int h  = bh % H_;

    __shared__ float qs[64][65];
    __shared__ float ks[64][65];   // reused for V tile
    __shared__ float ss[64][65];   // score tile -> probability tile
    __shared__ float m_sh[64], l_sh[64], alpha_sh[64];

    const int tid = threadIdx.x;
    const int tx = tid & 15;
    const int ty = tid >> 4;

    const float scale = 0.125f;    // 1/sqrt(DK)

    const float* Qb = Q + (size_t)bh * S_ * DK_ + (size_t)qt * 64 * DK_;
    const float* Kb = K + (size_t)bh * S_ * DK_;
    const float* Vb = V + (size_t)bh * S_ * DK_;
    const int*   mb = mask + b * S_;

    // Load Q tile (pre-scaled)
    for (int idx = tid; idx < 64 * 64; idx += 256) {
        const int r = idx >> 6, c = idx & 63;
        qs[r][c] = Qb[r * DK_ + c] * scale;
    }
    if (tid < 64) { m_sh[tid] = -INFINITY; l_sh[tid] = 0.0f; }

    float acc[4][4] = {};
    __syncthreads();

    for (int kt = 0; kt < S_ / 64; ++kt) {
        // Load K tile
        for (int idx = tid; idx < 64 * 64; idx += 256) {
            const int r = idx >> 6, c = idx & 63;
            ks[r][c] = Kb[(kt * 64 + r) * DK_ + c];
        }
        __syncthreads();

        // S tile = (Q*scale) . K^T, then mask, store to LDS
        float sacc[4][4] = {};
#pragma unroll 8
        for (int d = 0; d < 64; ++d) {
            float a[4], w[4];
#pragma unroll
            for (int i = 0; i < 4; ++i) a[i] = qs[ty * 4 + i][d];
#pragma unroll
            for (int j = 0; j < 4; ++j) w[j] = ks[tx * 4 + j][d];
#pragma unroll
            for (int i = 0; i < 4; ++i)
#pragma unroll
                for (int j = 0; j < 4; ++j)
                    sacc[i][j] += a[i] * w[j];
        }
#pragma unroll
        for (int j = 0; j < 4; ++j) {
            const int col = tx * 4 + j;
            const int msk = mb[kt * 64 + col];
#pragma unroll
            for (int i = 0; i < 4; ++i) {
                ss[ty * 4 + i][col] = (msk == 0) ? -1e9f : sacc[i][j];
            }
        }
        __syncthreads();

        // All threads: load V tile into ks (K tile fully consumed above).
        for (int idx = tid; idx < 64 * 64; idx += 256) {
            const int r = idx >> 6, c = idx & 63;
            ks[r][c] = Vb[(kt * 64 + r) * DK_ + c];
        }
        // Threads 0..63: online-softmax pass over their row of ss.
        if (tid < 64) {
            const int r = tid;
            const float mprev = m_sh[r];
            float mx = mprev;
            for (int c = 0; c < 64; ++c) mx = fmaxf(mx, ss[r][c]);
            const float alpha = __expf(mprev - mx);   // expf(-inf)=0 first iter
            float sum = 0.0f;
            for (int c = 0; c < 64; ++c) {
                const float p = __expf(ss[r][c] - mx);
                ss[r][c] = p;
                sum += p;
            }
            l_sh[r] = l_sh[r] * alpha + sum;
            m_sh[r] = mx;
            alpha_sh[r] = alpha;
        }
        __syncthreads();

        // Rescale running O and accumulate P.V
#pragma unroll
        for (int i = 0; i < 4; ++i) {
            const float al = alpha_sh[ty * 4 + i];
#pragma unroll
            for (int j = 0; j < 4; ++j) acc[i][j] *= al;
        }
#pragma unroll 8
        for (int d = 0; d < 64; ++d) {
            float p[4], v[4];
#pragma unroll
            for (int i = 0; i < 4; ++i) p[i] = ss[ty * 4 + i][d];
#pragma unroll
            for (int j = 0; j < 4; ++j) v[j] = ks[d][tx * 4 + j];
#pragma unroll
            for (int i = 0; i < 4; ++i)
#pragma unroll
                for (int j = 0; j < 4; ++j)
                    acc[i][j] += p[i] * v[j];
        }
        __syncthreads();   // protect ks/ss before next tile's loads
    }

    // Epilogue: O = acc / l, write into X[b, s, h*DK + dk]
#pragma unroll
    for (int i = 0; i < 4; ++i) {
        const int r = ty * 4 + i;
        const float inv = 1.0f / l_sh[r];
        const int srow = qt * 64 + r;
#pragma unroll
        for (int j = 0; j < 4; ++j) {
            X[((size_t)(b * S_ + srow)) * D_ + h * DK_ + tx * 4 + j] =
                acc[i][j] * inv;
        }
    }
}

// ---------------------------------------------------------------------------
extern "C" void kernel_launch(void* const* d_in, const int* in_sizes, int n_in,
                              void* d_out, int out_size, void* d_ws, size_t ws_size,
                              hipStream_t stream)
{
    (void)in_sizes; (void)n_in; (void)out_size; (void)ws_size;

    const float* query = (const float*)d_in[0];
    const float* key   = (const float*)d_in[1];
    const float* value = (const float*)d_in[2];
    const int*   mask  = (const int*)d_in[3];
    const float* wq    = (const float*)d_in[4];
    const float* bq    = (const float*)d_in[5];
    const float* wk    = (const float*)d_in[6];
    const float* bk    = (const float*)d_in[7];
    const float* wv    = (const float*)d_in[8];
    const float* bv    = (const float*)d_in[9];
    const float* wo    = (const float*)d_in[10];
    const float* bo    = (const float*)d_in[11];
    float* out = (float*)d_out;

    const size_t headElems = (size_t)B_ * H_ * S_ * DK_;  // 4,194,304
    float* Qws = (float*)d_ws;
    float* Kws = Qws + headElems;
    float* Vws = Kws + headElems;
    float* Xws = Vws + headElems;

    const dim3 blk(256);
    const dim3 gridProj(D_ / 64, (B_ * S_) / 64);   // (16, 64)

    proj_kernel<<<gridProj, blk, 0, stream>>>(query, wq, bq, Qws, 1);
    proj_kernel<<<gridProj, blk, 0, stream>>>(key,   wk, bk, Kws, 1);
    proj_kernel<<<gridProj, blk, 0, stream>>>(value, wv, bv, Vws, 1);

    const dim3 gridAttn(B_ * H_ * (S_ / 64));       // 1024
    attn_kernel<<<gridAttn, blk, 0, stream>>>(Qws, Kws, Vws, mask, Xws);

    proj_kernel<<<gridProj, blk, 0, stream>>>(Xws, wo, bo, out, 0);
}

// Round 2
// 320.643 us; speedup vs baseline: 5.9063x; 5.9063x over previous
//
#include <hip/hip_runtime.h>
#include <math.h>

#define B_  2
#define S_  2048
#define D_  1024
#define H_  16
#define DK_ 64

typedef unsigned short u16;
typedef __bf16 bf16x8 __attribute__((ext_vector_type(8)));
typedef float f32x4 __attribute__((ext_vector_type(4)));

typedef const __attribute__((address_space(1))) void* gas1_t;
typedef __attribute__((address_space(3))) void* las3_t;

__device__ __forceinline__ void gload_lds16(const void* g, void* l) {
    // async global->LDS, 16B per lane; LDS dst = wave-uniform base + lane*16
    __builtin_amdgcn_global_load_lds((gas1_t)g, (las3_t)l, 16, 0, 0);
}

__device__ __forceinline__ u16 f2bf(float f) {
    union { float f; unsigned u; } v; v.f = f;
    return (u16)((v.u + 0x7fffu + ((v.u >> 16) & 1u)) >> 16);   // RNE
}

// ---------------------------------------------------------------------------
// fp32 -> bf16 cast, vectorized
// ---------------------------------------------------------------------------
__global__ __launch_bounds__(256)
void cast_bf16_k(const float* __restrict__ in, u16* __restrict__ out, int n4)
{
    const int i = blockIdx.x * 256 + threadIdx.x;
    if (i < n4) {
        const float4 v = ((const float4*)in)[i];
        ushort4 o;
        o.x = f2bf(v.x); o.y = f2bf(v.y); o.z = f2bf(v.z); o.w = f2bf(v.w);
        ((ushort4*)out)[i] = o;
    }
}

// ---------------------------------------------------------------------------
// bf16 NT GEMM: C[m,n] = sum_k A[m,k] * W[n,k] + bias[n]
// M = 4096 (BM=128), K = 1024, N = 1024. BK=32, 4 waves in 2x2.
// mode 0: fp32 out[m*D+n]
// mode 1: bf16 out[((b*H+h)*S+s)*DK+dk], value scaled by `scale`
// mode 2: bf16 out[((b*H+h)*DK+dk)*S+s]  (V transposed for attention)
// ---------------------------------------------------------------------------
template<int BN>
__device__ __forceinline__ void gemm_body(
    const u16* __restrict__ A, const u16* __restrict__ W,
    const float* __restrict__ bias, void* __restrict__ outp,
    float scale, int mode)
{
    constexpr int NJ = BN / 32;
    __shared__ u16 sA[128 * 32];
    __shared__ u16 sW[BN * 32];

    const int tid  = threadIdx.x;
    const int wave = tid >> 6, lane = tid & 63;
    const int quad = lane >> 4, l16 = lane & 15;
    const int m0 = blockIdx.y * 128;
    const int n0 = blockIdx.x * BN;
    const int wm = (wave >> 1) * 64;
    const int wn = (wave & 1) * (BN / 2);
    const int lrow = lane >> 2;          // 0..15 within 16-row staging group
    const int lcol = (lane & 3) * 8;     // elem offset within 32-elem row

    f32x4 acc[4][NJ];
    const f32x4 zero = {0.f, 0.f, 0.f, 0.f};
#pragma unroll
    for (int i = 0; i < 4; ++i)
#pragma unroll
        for (int j = 0; j < NJ; ++j) acc[i][j] = zero;

    for (int k0 = 0; k0 < D_; k0 += 32) {
        const int t0 = wave, t1 = wave + 4;
        gload_lds16(A + (size_t)(m0 + t0 * 16 + lrow) * D_ + k0 + lcol, sA + t0 * 512);
        gload_lds16(A + (size_t)(m0 + t1 * 16 + lrow) * D_ + k0 + lcol, sA + t1 * 512);
        if (BN == 128) {
            gload_lds16(W + (size_t)(n0 + t0 * 16 + lrow) * D_ + k0 + lcol, sW + t0 * 512);
            gload_lds16(W + (size_t)(n0 + t1 * 16 + lrow) * D_ + k0 + lcol, sW + t1 * 512);
        } else {
            gload_lds16(W + (size_t)(n0 + wave * 16 + lrow) * D_ + k0 + lcol, sW + wave * 512);
        }
        __syncthreads();

        bf16x8 af[4], bfr[NJ];
#pragma unroll
        for (int i = 0; i < 4; ++i)
            af[i] = *(const bf16x8*)(sA + (wm + i * 16 + l16) * 32 + quad * 8);
#pragma unroll
        for (int j = 0; j < NJ; ++j)
            bfr[j] = *(const bf16x8*)(sW + (wn + j * 16 + l16) * 32 + quad * 8);
#pragma unroll
        for (int i = 0; i < 4; ++i)
#pragma unroll
            for (int j = 0; j < NJ; ++j)
                acc[i][j] = __builtin_amdgcn_mfma_f32_16x16x32_bf16(af[i], bfr[j], acc[i][j], 0, 0, 0);
        __syncthreads();
    }

    // Epilogue. C frag: row = quad*4+reg, col = lane&15  [m89/m91 verified]
#pragma unroll
    for (int i = 0; i < 4; ++i) {
#pragma unroll
        for (int j = 0; j < NJ; ++j) {
            const int n = n0 + wn + j * 16 + l16;
            const float bn = bias[n];
#pragma unroll
            for (int r = 0; r < 4; ++r) {
                const int m = m0 + wm + i * 16 + quad * 4 + r;
                const float v = acc[i][j][r] + bn;
                if (mode == 0) {
                    ((float*)outp)[(size_t)m * D_ + n] = v;
                } else {
                    const u16 hv = f2bf(v * scale);
                    const int b = m >> 11, s = m & (S_ - 1);
                    const int h = n >> 6, dk = n & 63;
                    if (mode == 1)
                        ((u16*)outp)[(((size_t)(b * H_ + h)) * S_ + s) * DK_ + dk] = hv;
                    else
                        ((u16*)outp)[(((size_t)(b * H_ + h)) * DK_ + dk) * S_ + s] = hv;
                }
            }
        }
    }
}

__global__ __launch_bounds__(256)
void qkv_gemm(const u16* __restrict__ qin, const u16* __restrict__ kin, const u16* __restrict__ vin,
              const u16* __restrict__ wqb, const u16* __restrict__ wkb, const u16* __restrict__ wvb,
              const float* __restrict__ bq, const float* __restrict__ bk, const float* __restrict__ bv,
              u16* __restrict__ Qp, u16* __restrict__ Kp, u16* __restrict__ Vp)
{
    const int z = blockIdx.z;
    const u16* A = (z == 0) ? qin : (z == 1) ? kin : vin;
    const u16* W = (z == 0) ? wqb : (z == 1) ? wkb : wvb;
    const float* bias = (z == 0) ? bq : (z == 1) ? bk : bv;
    u16* outp = (z == 0) ? Qp : (z == 1) ? Kp : Vp;
    // Q pre-scaled by log2(e)/sqrt(DK) so softmax works in exp2 domain
    const float scale = (z == 0) ? 0.18033688011112042f : 1.0f;
    const int mode = (z == 2) ? 2 : 1;
    gemm_body<128>(A, W, bias, outp, scale, mode);
}

__global__ __launch_bounds__(256)
void out_gemm(const u16* __restrict__ Xc, const u16* __restrict__ wob,
              const float* __restrict__ bo, float* __restrict__ out)
{
    gemm_body<64>(Xc, wob, bo, out, 1.0f, 0);
}

// ---------------------------------------------------------------------------
// MFMA flash attention. Block = 256 thr (4 waves), 128 q-rows per block,
// 64-key tiles. Qp/Kp: [B,H,S,64] bf16 (Q pre-scaled), Vt: [B,H,64,S] bf16.
// mask [B,1,1,S] int32. Output Xc: [B,S,D] bf16 (merge-heads fused).
// Per wave: 32 q-rows. Softmax state (m,l) lives in regs, replicated across
// the 16-lane quad group. P goes through swizzled LDS to A-frag layout.
// ---------------------------------------------------------------------------
__global__ __launch_bounds__(256)
void attn_mfma(const u16* __restrict__ Qp, const u16* __restrict__ Kp,
               const u16* __restrict__ Vt, const int* __restrict__ mask,
               u16* __restrict__ Xc)
{
    __shared__ u16 sQ[128 * 64];   // 16 KB; reused as P (4 KB per wave)
    __shared__ u16 sK[64 * 64];    // 8 KB
    __shared__ u16 sV[64 * 64];    // 8 KB (Vt tile: [d][key])

    const int tid = threadIdx.x;
    const int wave = tid >> 6, lane = tid & 63;
    const int quad = lane >> 4, l16 = lane & 15;
    const int qt = blockIdx.x & 15;
    const int bh = blockIdx.x >> 4;
    const int b  = bh >> 4;
    const int h  = bh & 15;
    const int lrow8 = lane >> 3;         // 0..7 (128B rows)
    const int lcol8 = (lane & 7) * 8;

    const u16* Qb = Qp + ((size_t)bh * S_ + qt * 128) * DK_;
    const u16* Kb = Kp + (size_t)bh * S_ * DK_;
    const u16* Vb = Vt + (size_t)bh * DK_ * S_;
    const int* mb = mask + b * S_;

    // stage Q tile (16 KB = 16 insts)
#pragma unroll
    for (int t = 0; t < 4; ++t) {
        const int tt = wave + t * 4;
        gload_lds16(Qb + (size_t)(tt * 8 + lrow8) * DK_ + lcol8, sQ + tt * 512);
    }
    __syncthreads();
    // preload Q A-frags: A[m=lane&15][k=quad*8+j]
    bf16x8 qf[2][2];
#pragma unroll
    for (int im = 0; im < 2; ++im)
#pragma unroll
        for (int ks = 0; ks < 2; ++ks)
            qf[im][ks] = *(const bf16x8*)(sQ + (wave * 32 + im * 16 + l16) * 64 + ks * 32 + quad * 8);
    __syncthreads();   // everyone done reading sQ -> reuse as P

    u16* sP = sQ + wave * 2048;   // this wave's 32x64 P tile

    f32x4 oacc[2][4];
    const f32x4 zero = {0.f, 0.f, 0.f, 0.f};
#pragma unroll
    for (int im = 0; im < 2; ++im)
#pragma unroll
        for (int nd = 0; nd < 4; ++nd) oacc[im][nd] = zero;
    float mrow[2][4], lsum[2][4];
#pragma unroll
    for (int im = 0; im < 2; ++im)
#pragma unroll
        for (int r = 0; r < 4; ++r) { mrow[im][r] = -INFINITY; lsum[im][r] = 0.f; }

    for (int kt = 0; kt < S_ / 64; ++kt) {
        // stage K tile + Vt tile (8 KB each)
#pragma unroll
        for (int t = 0; t < 2; ++t) {
            const int tt = wave + t * 4;
            gload_lds16(Kb + (size_t)(kt * 64 + tt * 8 + lrow8) * DK_ + lcol8, sK + tt * 512);
            gload_lds16(Vb + (size_t)(tt * 8 + lrow8) * S_ + kt * 64 + lcol8, sV + tt * 512);
        }
        int mk[4];
#pragma unroll
        for (int in = 0; in < 4; ++in) mk[in] = mb[kt * 64 + in * 16 + l16];
        __syncthreads();

        // S' = (Q*log2e/8) . K^T   (C frag: row=quad*4+r, col=l16)
        f32x4 sfr[2][4];
#pragma unroll
        for (int im = 0; im < 2; ++im)
#pragma unroll
            for (int in = 0; in < 4; ++in) sfr[im][in] = zero;
#pragma unroll
        for (int in = 0; in < 4; ++in) {
#pragma unroll
            for (int ks = 0; ks < 2; ++ks) {
                const bf16x8 kf = *(const bf16x8*)(sK + (in * 16 + l16) * 64 + ks * 32 + quad * 8);
#pragma unroll
                for (int im = 0; im < 2; ++im)
                    sfr[im][in] = __builtin_amdgcn_mfma_f32_16x16x32_bf16(qf[im][ks], kf, sfr[im][in], 0, 0, 0);
            }
        }
        // mask (key-position mask, col = kt*64 + in*16 + l16)
#pragma unroll
        for (int in = 0; in < 4; ++in) {
#pragma unroll
            for (int im = 0; im < 2; ++im)
#pragma unroll
                for (int r = 0; r < 4; ++r)
                    sfr[im][in][r] = (mk[in] == 0) ? -1e9f : sfr[im][in][r];
        }
        // online softmax (exp2 domain); row r of quad group spread over 16 lanes
#pragma unroll
        for (int im = 0; im < 2; ++im) {
#pragma unroll
            for (int r = 0; r < 4; ++r) {
                float v = fmaxf(fmaxf(sfr[im][0][r], sfr[im][1][r]),
                                fmaxf(sfr[im][2][r], sfr[im][3][r]));
                v = fmaxf(v, __shfl_xor(v, 1));
                v = fmaxf(v, __shfl_xor(v, 2));
                v = fmaxf(v, __shfl_xor(v, 4));
                v = fmaxf(v, __shfl_xor(v, 8));
                const float mnew = fmaxf(mrow[im][r], v);
                const float alpha = __builtin_amdgcn_exp2f(mrow[im][r] - mnew); // -inf -> 0
                mrow[im][r] = mnew;
                float rs = 0.f;
#pragma unroll
                for (int in = 0; in < 4; ++in) {
                    const float p = __builtin_amdgcn_exp2f(sfr[im][in][r] - mnew);
                    sfr[im][in][r] = p;
                    rs += p;
                }
                rs += __shfl_xor(rs, 1);
                rs += __shfl_xor(rs, 2);
                rs += __shfl_xor(rs, 4);
                rs += __shfl_xor(rs, 8);
                lsum[im][r] = lsum[im][r] * alpha + rs;
#pragma unroll
                for (int nd = 0; nd < 4; ++nd) oacc[im][nd][r] *= alpha;
            }
        }
        // write P to LDS, quad-rotated columns (conflict-free b16 writes):
        // phys_col = (col + (row&12)*4) & 63
#pragma unroll
        for (int im = 0; im < 2; ++im)
#pragma unroll
            for (int in = 0; in < 4; ++in)
#pragma unroll
                for (int r = 0; r < 4; ++r) {
                    const int row = im * 16 + quad * 4 + r;
                    const int colp = (in * 16 + l16 + quad * 16) & 63;
                    sP[row * 64 + colp] = f2bf(sfr[im][in][r]);
                }
        __syncthreads();
        // PV: A = P (swizzle-corrected), B = Vt tile
#pragma unroll
        for (int ks = 0; ks < 2; ++ks) {
            bf16x8 pf[2];
#pragma unroll
            for (int im = 0; im < 2; ++im) {
                const int start = (ks * 32 + quad * 8 + (l16 & 12) * 4) & 63;
                pf[im] = *(const bf16x8*)(sP + (im * 16 + l16) * 64 + start);
            }
#pragma unroll
            for (int nd = 0; nd < 4; ++nd) {
                const bf16x8 vf = *(const bf16x8*)(sV + (nd * 16 + l16) * 64 + ks * 32 + quad * 8);
#pragma unroll
                for (int im = 0; im < 2; ++im)
                    oacc[im][nd] = __builtin_amdgcn_mfma_f32_16x16x32_bf16(pf[im], vf, oacc[im][nd], 0, 0, 0);
            }
        }
        __syncthreads();
    }

    // epilogue: O /= l, write merged-heads bf16
#pragma unroll
    for (int im = 0; im < 2; ++im)
#pragma unroll
        for (int r = 0; r < 4; ++r) {
            const int s = qt * 128 + wave * 32 + im * 16 + quad * 4 + r;
            const float inv = 1.0f / lsum[im][r];
#pragma unroll
            for (int nd = 0; nd < 4; ++nd)
                Xc[((size_t)(b * S_ + s)) * D_ + h * 64 + nd * 16 + l16] =
                    f2bf(oacc[im][nd][r] * inv);
        }
}

// ---------------------------------------------------------------------------
extern "C" void kernel_launch(void* const* d_in, const int* in_sizes, int n_in,
                              void* d_out, int out_size, void* d_ws, size_t ws_size,
                              hipStream_t stream)
{
    (void)in_sizes; (void)n_in; (void)out_size; (void)ws_size;

    const float* query = (const float*)d_in[0];
    const float* key   = (const float*)d_in[1];
    const float* value = (const float*)d_in[2];
    const int*   mask  = (const int*)d_in[3];
    const float* wq    = (const float*)d_in[4];
    const float* bq    = (const float*)d_in[5];
    const float* wk    = (const float*)d_in[6];
    const float* bk    = (const float*)d_in[7];
    const float* wv    = (const float*)d_in[8];
    const float* bv    = (const float*)d_in[9];
    const float* wo    = (const float*)d_in[10];
    const float* bo    = (const float*)d_in[11];

    const size_t NE = (size_t)B_ * S_ * D_;   // 4,194,304
    const size_t WE = (size_t)D_ * D_;        // 1,048,576

    u16* qb  = (u16*)d_ws;      // bf16 inputs
    u16* kb  = qb + NE;
    u16* vb  = kb + NE;
    u16* wqb = vb + NE;         // bf16 weights
    u16* wkb = wqb + WE;
    u16* wvb = wkb + WE;
    u16* wob = wvb + WE;
    u16* Qp  = wob + WE;        // projected heads
    u16* Kp  = Qp + NE;
    u16* Vp  = Kp + NE;
    u16* Xc  = qb;              // alias: qb is dead after qkv_gemm

    cast_bf16_k<<<4096, 256, 0, stream>>>(query, qb, (int)(NE / 4));
    cast_bf16_k<<<4096, 256, 0, stream>>>(key,   kb, (int)(NE / 4));
    cast_bf16_k<<<4096, 256, 0, stream>>>(value, vb, (int)(NE / 4));
    cast_bf16_k<<<1024, 256, 0, stream>>>(wq, wqb, (int)(WE / 4));
    cast_bf16_k<<<1024, 256, 0, stream>>>(wk, wkb, (int)(WE / 4));
    cast_bf16_k<<<1024, 256, 0, stream>>>(wv, wvb, (int)(WE / 4));
    cast_bf16_k<<<1024, 256, 0, stream>>>(wo, wob, (int)(WE / 4));

    qkv_gemm<<<dim3(D_ / 128, (B_ * S_) / 128, 3), 256, 0, stream>>>(
        qb, kb, vb, wqb, wkb, wvb, bq, bk, bv, Qp, Kp, Vp);

    attn_mfma<<<dim3(B_ * H_ * (S_ / 128)), 256, 0, stream>>>(Qp, Kp, Vp, mask, Xc);

    out_gemm<<<dim3(D_ / 64, (B_ * S_) / 128), 256, 0, stream>>>(Xc, wob, bo, (float*)d_out);
}

// Round 3
// 250.328 us; speedup vs baseline: 7.5653x; 1.2809x over previous
//
#include <hip/hip_runtime.h>
#include <math.h>

#define B_  2
#define S_  2048
#define D_  1024
#define H_  16
#define DK_ 64
#define NT_ (S_ / 64)   // 32 key tiles

typedef unsigned short u16;
typedef unsigned int u32;
typedef __bf16 bf16x8 __attribute__((ext_vector_type(8)));
typedef float f32x4 __attribute__((ext_vector_type(4)));

typedef const __attribute__((address_space(1))) void* gas1_t;
typedef __attribute__((address_space(3))) void* las3_t;

__device__ __forceinline__ void gload_lds16(const void* g, void* l) {
    // async global->LDS, 16B per lane; LDS dst = wave-uniform base + lane*16
    __builtin_amdgcn_global_load_lds((gas1_t)g, (las3_t)l, 16, 0, 0);
}

__device__ __forceinline__ u16 f2bf(float f) {
    union { float f; unsigned u; } v; v.f = f;
    return (u16)((v.u + 0x7fffu + ((v.u >> 16) & 1u)) >> 16);   // RNE
}

// pack two f32 into two bf16 (round-half-away) in one u32: [lo | hi<<16]
__device__ __forceinline__ u32 pack_bf16_2(float lo, float hi) {
    union { float f; u32 u; } a, b;
    a.f = lo; b.f = hi;
    return __builtin_amdgcn_perm(b.u + 0x8000u, a.u + 0x8000u, 0x07060302u);
}

// ---------------------------------------------------------------------------
// One fused fp32 -> bf16 cast over all 7 tensors (3 x 4M elems, 4 x 1M elems)
// ---------------------------------------------------------------------------
__global__ __launch_bounds__(256)
void cast_all(const float* __restrict__ q, const float* __restrict__ k,
              const float* __restrict__ v, const float* __restrict__ wq,
              const float* __restrict__ wk, const float* __restrict__ wv,
              const float* __restrict__ wo,
              u16* __restrict__ qb, u16* __restrict__ kb, u16* __restrict__ vb,
              u16* __restrict__ wqb, u16* __restrict__ wkb, u16* __restrict__ wvb,
              u16* __restrict__ wob)
{
    const int i = blockIdx.x * 256 + threadIdx.x;   // float4 index
    const float* src; u16* dst; int off;
    if (i < 3 * 1048576) {
        const int seg = i >> 20; off = i & 1048575;
        src = (seg == 0) ? q : (seg == 1) ? k : v;
        dst = (seg == 0) ? qb : (seg == 1) ? kb : vb;
    } else {
        const int j = i - 3 * 1048576;
        const int seg = j >> 18; off = j & 262143;
        src = (seg == 0) ? wq : (seg == 1) ? wk : (seg == 2) ? wv : wo;
        dst = (seg == 0) ? wqb : (seg == 1) ? wkb : (seg == 2) ? wvb : wob;
    }
    const float4 val = ((const float4*)src)[off];
    uint2 o;
    o.x = pack_bf16_2(val.x, val.y);
    o.y = pack_bf16_2(val.z, val.w);
    ((uint2*)dst)[off] = o;
}

// ---------------------------------------------------------------------------
// bf16 NT GEMM: C[m,n] = sum_k A[m,k] * W[n,k] + bias[n]
// M = 4096 (BM=128), K = 1024, N = 1024. BK=32, 4 waves in 2x2.
// mode 0: fp32 out[m*D+n]
// mode 1: bf16 out[((b*H+h)*S+s)*DK+dk], value scaled by `scale`
// mode 2: bf16 out[((b*H+h)*DK+dk)*S+s]  (V transposed; packed b64 stores)
// ---------------------------------------------------------------------------
template<int BN>
__device__ __forceinline__ void gemm_body(
    const u16* __restrict__ A, const u16* __restrict__ W,
    const float* __restrict__ bias, void* __restrict__ outp,
    float scale, int mode)
{
    constexpr int NJ = BN / 32;
    __shared__ u16 sA[128 * 32];
    __shared__ u16 sW[BN * 32];

    const int tid  = threadIdx.x;
    const int wave = tid >> 6, lane = tid & 63;
    const int quad = lane >> 4, l16 = lane & 15;
    const int m0 = blockIdx.y * 128;
    const int n0 = blockIdx.x * BN;
    const int wm = (wave >> 1) * 64;
    const int wn = (wave & 1) * (BN / 2);
    const int lrow = lane >> 2;          // 0..15 within 16-row staging group
    const int lcol = (lane & 3) * 8;     // elem offset within 32-elem row

    f32x4 acc[4][NJ];
    const f32x4 zero = {0.f, 0.f, 0.f, 0.f};
#pragma unroll
    for (int i = 0; i < 4; ++i)
#pragma unroll
        for (int j = 0; j < NJ; ++j) acc[i][j] = zero;

    for (int k0 = 0; k0 < D_; k0 += 32) {
        const int t0 = wave, t1 = wave + 4;
        gload_lds16(A + (size_t)(m0 + t0 * 16 + lrow) * D_ + k0 + lcol, sA + t0 * 512);
        gload_lds16(A + (size_t)(m0 + t1 * 16 + lrow) * D_ + k0 + lcol, sA + t1 * 512);
        if (BN == 128) {
            gload_lds16(W + (size_t)(n0 + t0 * 16 + lrow) * D_ + k0 + lcol, sW + t0 * 512);
            gload_lds16(W + (size_t)(n0 + t1 * 16 + lrow) * D_ + k0 + lcol, sW + t1 * 512);
        } else {
            gload_lds16(W + (size_t)(n0 + wave * 16 + lrow) * D_ + k0 + lcol, sW + wave * 512);
        }
        __syncthreads();

        bf16x8 af[4], bfr[NJ];
#pragma unroll
        for (int i = 0; i < 4; ++i)
            af[i] = *(const bf16x8*)(sA + (wm + i * 16 + l16) * 32 + quad * 8);
#pragma unroll
        for (int j = 0; j < NJ; ++j)
            bfr[j] = *(const bf16x8*)(sW + (wn + j * 16 + l16) * 32 + quad * 8);
#pragma unroll
        for (int i = 0; i < 4; ++i)
#pragma unroll
            for (int j = 0; j < NJ; ++j)
                acc[i][j] = __builtin_amdgcn_mfma_f32_16x16x32_bf16(af[i], bfr[j], acc[i][j], 0, 0, 0);
        __syncthreads();
    }

    // Epilogue. C frag: row = quad*4+reg, col = lane&15
#pragma unroll
    for (int i = 0; i < 4; ++i) {
#pragma unroll
        for (int j = 0; j < NJ; ++j) {
            const int n = n0 + wn + j * 16 + l16;
            const float bn = bias[n];
            if (mode == 2) {
                const int mbase = m0 + wm + i * 16 + quad * 4;
                const int b = mbase >> 11, s = mbase & (S_ - 1);
                const int h = n >> 6, dk = n & 63;
                uint2 o;
                o.x = pack_bf16_2(acc[i][j][0] + bn, acc[i][j][1] + bn);
                o.y = pack_bf16_2(acc[i][j][2] + bn, acc[i][j][3] + bn);
                *(uint2*)((u16*)outp + (((size_t)(b * H_ + h)) * DK_ + dk) * S_ + s) = o;
            } else {
#pragma unroll
                for (int r = 0; r < 4; ++r) {
                    const int m = m0 + wm + i * 16 + quad * 4 + r;
                    const float v = acc[i][j][r] + bn;
                    if (mode == 0) {
                        ((float*)outp)[(size_t)m * D_ + n] = v;
                    } else {
                        const u16 hv = f2bf(v * scale);
                        const int b = m >> 11, s = m & (S_ - 1);
                        const int h = n >> 6, dk = n & 63;
                        ((u16*)outp)[(((size_t)(b * H_ + h)) * S_ + s) * DK_ + dk] = hv;
                    }
                }
            }
        }
    }
}

__global__ __launch_bounds__(256)
void qkv_gemm(const u16* __restrict__ qin, const u16* __restrict__ kin, const u16* __restrict__ vin,
              const u16* __restrict__ wqb, const u16* __restrict__ wkb, const u16* __restrict__ wvb,
              const float* __restrict__ bq, const float* __restrict__ bk, const float* __restrict__ bv,
              u16* __restrict__ Qp, u16* __restrict__ Kp, u16* __restrict__ Vp)
{
    const int z = blockIdx.z;
    const u16* A = (z == 0) ? qin : (z == 1) ? kin : vin;
    const u16* W = (z == 0) ? wqb : (z == 1) ? wkb : wvb;
    const float* bias = (z == 0) ? bq : (z == 1) ? bk : bv;
    u16* outp = (z == 0) ? Qp : (z == 1) ? Kp : Vp;
    // Q pre-scaled by log2(e)/sqrt(DK) so softmax works in exp2 domain
    const float scale = (z == 0) ? 0.18033688011112042f : 1.0f;
    const int mode = (z == 2) ? 2 : 1;
    gemm_body<128>(A, W, bias, outp, scale, mode);
}

__global__ __launch_bounds__(256)
void out_gemm(const u16* __restrict__ Xc, const u16* __restrict__ wob,
              const float* __restrict__ bo, float* __restrict__ out)
{
    gemm_body<128>(Xc, wob, bo, out, 1.0f, 0);
}

// ---------------------------------------------------------------------------
// MFMA flash attention, S^T orientation + fixed-shift exp2 softmax.
// Block = 256 thr (4 waves), 128 q-rows per block, 64-key tiles, K/V double-
// buffered. All LDS tiles use chunk^row XOR swizzle (16B chunks) so fragment
// ds_read_b128 are conflict-free despite 128B rows.
//  - QK^T computed as S^T = K . Q^T -> C frag: row=key(quad*4+r), col=q(l16);
//    softmax sum over keys is per-lane, mask folds into the MFMA acc init.
//  - P^T frag regs = 4 consecutive k for fixed q -> packed ds_write_b64.
//  - PV: A = P (m=q), B = V^T tile (n=d) -> O frag row=q, col=d.
// ---------------------------------------------------------------------------
__global__ __launch_bounds__(256)
void attn_mfma(const u16* __restrict__ Qp, const u16* __restrict__ Kp,
               const u16* __restrict__ Vt, const int* __restrict__ mask,
               u16* __restrict__ Xc)
{
    __shared__ u16 sQ[128 * 64];      // 16 KB
    __shared__ u16 sP[128 * 64];      // 16 KB (4 KB per wave)
    __shared__ u16 sK[2][64 * 64];    // 16 KB double-buffered
    __shared__ u16 sV[2][64 * 64];    // 16 KB double-buffered

    const int tid  = threadIdx.x;
    const int wave = tid >> 6, lane = tid & 63;
    const int quad = lane >> 4, l16 = lane & 15;
    const int qt = blockIdx.x & 15;
    const int bh = blockIdx.x >> 4;
    const int b  = bh >> 4;
    const int h  = bh & 15;
    const int srow = lane >> 3;                  // staging row within 8-row group
    const int scol = ((lane & 7) ^ srow) * 8;    // swizzled source column (u16)
    const int sw7  = l16 & 7;                    // row&7 for fragment reads

    const u16* Qb = Qp + ((size_t)bh * S_ + qt * 128) * DK_;
    const u16* Kb = Kp + (size_t)bh * S_ * DK_;
    const u16* Vb = Vt + (size_t)bh * DK_ * S_;
    const int* mb = mask + b * S_;

    // stage Q tile (128x64) + K/V tile 0, all swizzled
#pragma unroll
    for (int t = 0; t < 4; ++t) {
        const int tt = wave + t * 4;
        gload_lds16(Qb + (size_t)(tt * 8 + srow) * DK_ + scol, sQ + tt * 512);
    }
#pragma unroll
    for (int t = 0; t < 2; ++t) {
        const int tt = wave + t * 4;
        gload_lds16(Kb + (size_t)(tt * 8 + srow) * DK_ + scol, &sK[0][tt * 512]);
        gload_lds16(Vb + (size_t)(tt * 8 + srow) * S_ + scol, &sV[0][tt * 512]);
    }
    __syncthreads();

    // preload Q as B-frags: B[n=q=l16][k=quad*8+j], per wave q in [w*32, w*32+32)
    bf16x8 qf[2][2];
#pragma unroll
    for (int iq = 0; iq < 2; ++iq)
#pragma unroll
        for (int ks = 0; ks < 2; ++ks) {
            const int row = wave * 32 + iq * 16 + l16;
            const int phys = (ks * 4 + quad) ^ sw7;
            qf[iq][ks] = *(const bf16x8*)(sQ + row * 64 + phys * 8);
        }

    u16* sPw = sP + wave * 2048;   // this wave's 32x64 P tile

    f32x4 oacc[2][4];              // [imA(q)][nd(d)]
    const f32x4 zero = {0.f, 0.f, 0.f, 0.f};
#pragma unroll
    for (int im = 0; im < 2; ++im)
#pragma unroll
        for (int nd = 0; nd < 4; ++nd) oacc[im][nd] = zero;
    f32x4 lsum4[2] = {zero, zero}; // [iq], component = in

    int4 mk4[4];
#pragma unroll
    for (int in = 0; in < 4; ++in)
        mk4[in] = *(const int4*)(mb + in * 16 + quad * 4);

    for (int kt = 0; kt < NT_; ++kt) {
        __syncthreads();            // cur buf staged (vmcnt drained); prev PV done
        const int cur = kt & 1;

        // prefetch next tile's mask (key-position mask, per-lane rows)
        int4 mkn[4];
        const int ktn = (kt < NT_ - 1) ? kt + 1 : kt;
#pragma unroll
        for (int in = 0; in < 4; ++in)
            mkn[in] = *(const int4*)(mb + ktn * 64 + in * 16 + quad * 4);

        // init S^T acc with mask bias (masked key row -> -1e9 -> exp2 -> 0)
        f32x4 binit[4];
#pragma unroll
        for (int in = 0; in < 4; ++in) {
            binit[in][0] = mk4[in].x ? 0.f : -1e9f;
            binit[in][1] = mk4[in].y ? 0.f : -1e9f;
            binit[in][2] = mk4[in].z ? 0.f : -1e9f;
            binit[in][3] = mk4[in].w ? 0.f : -1e9f;
        }
        f32x4 sfr[2][4];
#pragma unroll
        for (int iq = 0; iq < 2; ++iq)
#pragma unroll
            for (int in = 0; in < 4; ++in) sfr[iq][in] = binit[in];

        // S^T = K . Q^T  (A = K rows -> m=key, B = Q -> n=q)
#pragma unroll
        for (int in = 0; in < 4; ++in) {
#pragma unroll
            for (int ks = 0; ks < 2; ++ks) {
                const int phys = (ks * 4 + quad) ^ sw7;
                const bf16x8 kf = *(const bf16x8*)(&sK[cur][(in * 16 + l16) * 64 + phys * 8]);
#pragma unroll
                for (int iq = 0; iq < 2; ++iq)
                    sfr[iq][in] = __builtin_amdgcn_mfma_f32_16x16x32_bf16(kf, qf[iq][ks], sfr[iq][in], 0, 0, 0);
            }
        }

        // exp2 (fixed shift), per-lane partial row sums, pack P -> LDS b64
#pragma unroll
        for (int iq = 0; iq < 2; ++iq) {
#pragma unroll
            for (int in = 0; in < 4; ++in) {
                const float p0 = __builtin_amdgcn_exp2f(sfr[iq][in][0]);
                const float p1 = __builtin_amdgcn_exp2f(sfr[iq][in][1]);
                const float p2 = __builtin_amdgcn_exp2f(sfr[iq][in][2]);
                const float p3 = __builtin_amdgcn_exp2f(sfr[iq][in][3]);
                lsum4[iq][in] += (p0 + p1) + (p2 + p3);
                uint2 o;
                o.x = pack_bf16_2(p0, p1);
                o.y = pack_bf16_2(p2, p3);
                // P[q][k]: q=iq*16+l16, k=in*16+quad*4+r ; chunk=(k>>3)^(q&7)
                const int pchunk = (in * 2 + (quad >> 1)) ^ sw7;
                *(uint2*)(sPw + (iq * 16 + l16) * 64 + pchunk * 8 + (quad & 1) * 4) = o;
            }
        }
#pragma unroll
        for (int in = 0; in < 4; ++in) mk4[in] = mkn[in];

        __syncthreads();            // P visible to all lanes of own wave's readers

        // stage next K/V tile into alt buffer (drains at next top barrier)
        if (kt < NT_ - 1) {
            const int alt = cur ^ 1;
#pragma unroll
            for (int t = 0; t < 2; ++t) {
                const int tt = wave + t * 4;
                gload_lds16(Kb + (size_t)((kt + 1) * 64 + tt * 8 + srow) * DK_ + scol, &sK[alt][tt * 512]);
                gload_lds16(Vb + (size_t)(tt * 8 + srow) * S_ + (kt + 1) * 64 + scol, &sV[alt][tt * 512]);
            }
        }

        // PV: A = P (m=q), B = V^T tile (n=d)
#pragma unroll
        for (int ks = 0; ks < 2; ++ks) {
            bf16x8 pf[2];
#pragma unroll
            for (int im = 0; im < 2; ++im) {
                const int phys = (ks * 4 + quad) ^ sw7;
                pf[im] = *(const bf16x8*)(sPw + (im * 16 + l16) * 64 + phys * 8);
            }
#pragma unroll
            for (int nd = 0; nd < 4; ++nd) {
                const int phys = (ks * 4 + quad) ^ sw7;
                const bf16x8 vf = *(const bf16x8*)(&sV[cur][(nd * 16 + l16) * 64 + phys * 8]);
#pragma unroll
                for (int im = 0; im < 2; ++im)
                    oacc[im][nd] = __builtin_amdgcn_mfma_f32_16x16x32_bf16(pf[im], vf, oacc[im][nd], 0, 0, 0);
            }
        }
    }

    // finalize lsum: in-lane over `in`, then across quads (keys) only
    float lq[2];
#pragma unroll
    for (int iq = 0; iq < 2; ++iq) {
        float v = (lsum4[iq][0] + lsum4[iq][1]) + (lsum4[iq][2] + lsum4[iq][3]);
        v += __shfl_xor(v, 16);
        v += __shfl_xor(v, 32);
        lq[iq] = v;
    }
    // transpose lsum (q in l16) -> O-frag rows (q in quad*4+r) via wave-private LDS
    float* sL = (float*)sPw;
    if (quad == 0) {
        sL[l16] = lq[0];
        sL[16 + l16] = lq[1];
    }
    float linv[2][4];
#pragma unroll
    for (int im = 0; im < 2; ++im)
#pragma unroll
        for (int r = 0; r < 4; ++r)
            linv[im][r] = __builtin_amdgcn_rcpf(sL[im * 16 + quad * 4 + r]);

    // write O (merge-heads) bf16
#pragma unroll
    for (int im = 0; im < 2; ++im)
#pragma unroll
        for (int r = 0; r < 4; ++r) {
            const int s = qt * 128 + wave * 32 + im * 16 + quad * 4 + r;
            const float inv = linv[im][r];
#pragma unroll
            for (int nd = 0; nd < 4; ++nd)
                Xc[((size_t)(b * S_ + s)) * D_ + h * 64 + nd * 16 + l16] =
                    f2bf(oacc[im][nd][r] * inv);
        }
}

// ---------------------------------------------------------------------------
extern "C" void kernel_launch(void* const* d_in, const int* in_sizes, int n_in,
                              void* d_out, int out_size, void* d_ws, size_t ws_size,
                              hipStream_t stream)
{
    (void)in_sizes; (void)n_in; (void)out_size; (void)ws_size;

    const float* query = (const float*)d_in[0];
    const float* key   = (const float*)d_in[1];
    const float* value = (const float*)d_in[2];
    const int*   mask  = (const int*)d_in[3];
    const float* wq    = (const float*)d_in[4];
    const float* bq    = (const float*)d_in[5];
    const float* wk    = (const float*)d_in[6];
    const float* bk    = (const float*)d_in[7];
    const float* wv    = (const float*)d_in[8];
    const float* bv    = (const float*)d_in[9];
    const float* wo    = (const float*)d_in[10];
    const float* bo    = (const float*)d_in[11];

    const size_t NE = (size_t)B_ * S_ * D_;   // 4,194,304
    const size_t WE = (size_t)D_ * D_;        // 1,048,576

    u16* qb  = (u16*)d_ws;      // bf16 inputs
    u16* kb  = qb + NE;
    u16* vb  = kb + NE;
    u16* wqb = vb + NE;         // bf16 weights
    u16* wkb = wqb + WE;
    u16* wvb = wkb + WE;
    u16* wob = wvb + WE;
    u16* Qp  = wob + WE;        // projected heads
    u16* Kp  = Qp + NE;
    u16* Vp  = Kp + NE;
    u16* Xc  = qb;              // alias: qb is dead after qkv_gemm

    cast_all<<<16384, 256, 0, stream>>>(query, key, value, wq, wk, wv, wo,
                                        qb, kb, vb, wqb, wkb, wvb, wob);

    qkv_gemm<<<dim3(D_ / 128, (B_ * S_) / 128, 3), 256, 0, stream>>>(
        qb, kb, vb, wqb, wkb, wvb, bq, bk, bv, Qp, Kp, Vp);

    attn_mfma<<<dim3(B_ * H_ * (S_ / 128)), 256, 0, stream>>>(Qp, Kp, Vp, mask, Xc);

    out_gemm<<<dim3(D_ / 128, (B_ * S_) / 128), 256, 0, stream>>>(Xc, wob, bo, (float*)d_out);
}

// Round 4
// 242.218 us; speedup vs baseline: 7.8186x; 1.0335x over previous
//
#include <hip/hip_runtime.h>
#include <math.h>

#define B_  2
#define S_  2048
#define D_  1024
#define H_  16
#define DK_ 64
#define NT_ (S_ / 64)   // 32 key tiles

typedef unsigned short u16;
typedef unsigned int u32;
typedef __bf16 bf16x8 __attribute__((ext_vector_type(8)));
typedef float f32x4 __attribute__((ext_vector_type(4)));

typedef const __attribute__((address_space(1))) void* gas1_t;
typedef __attribute__((address_space(3))) void* las3_t;

__device__ __forceinline__ void gload_lds16(const void* g, void* l) {
    // async global->LDS, 16B per lane; LDS dst = wave-uniform base + lane*16
    __builtin_amdgcn_global_load_lds((gas1_t)g, (las3_t)l, 16, 0, 0);
}

__device__ __forceinline__ u16 f2bf(float f) {
    union { float f; unsigned u; } v; v.f = f;
    return (u16)((v.u + 0x7fffu + ((v.u >> 16) & 1u)) >> 16);   // RNE
}

// pack two f32 into two bf16 (round-half-away) in one u32: [lo | hi<<16]
__device__ __forceinline__ u32 pack_bf16_2(float lo, float hi) {
    union { float f; u32 u; } a, b;
    a.f = lo; b.f = hi;
    return __builtin_amdgcn_perm(b.u + 0x8000u, a.u + 0x8000u, 0x07060302u);
}

// ---------------------------------------------------------------------------
// Fused fp32 -> bf16 cast over all 7 tensors + mask -> f32 bias (0 / -1e9)
// ---------------------------------------------------------------------------
__global__ __launch_bounds__(256)
void cast_all(const float* __restrict__ q, const float* __restrict__ k,
              const float* __restrict__ v, const float* __restrict__ wq,
              const float* __restrict__ wk, const float* __restrict__ wv,
              const float* __restrict__ wo, const int* __restrict__ mask,
              u16* __restrict__ qb, u16* __restrict__ kb, u16* __restrict__ vb,
              u16* __restrict__ wqb, u16* __restrict__ wkb, u16* __restrict__ wvb,
              u16* __restrict__ wob, float* __restrict__ mbias)
{
    const int i = blockIdx.x * 256 + threadIdx.x;   // float4 index
    if (i >= 4194304) {                             // mask tail: 4096 ints
        const int idx = i - 4194304;
        mbias[idx] = mask[idx] ? 0.0f : -1e9f;
        return;
    }
    const float* src; u16* dst; int off;
    if (i < 3 * 1048576) {
        const int seg = i >> 20; off = i & 1048575;
        src = (seg == 0) ? q : (seg == 1) ? k : v;
        dst = (seg == 0) ? qb : (seg == 1) ? kb : vb;
    } else {
        const int j = i - 3 * 1048576;
        const int seg = j >> 18; off = j & 262143;
        src = (seg == 0) ? wq : (seg == 1) ? wk : (seg == 2) ? wv : wo;
        dst = (seg == 0) ? wqb : (seg == 1) ? wkb : (seg == 2) ? wvb : wob;
    }
    const float4 val = ((const float4*)src)[off];
    uint2 o;
    o.x = pack_bf16_2(val.x, val.y);
    o.y = pack_bf16_2(val.z, val.w);
    ((uint2*)dst)[off] = o;
}

// ---------------------------------------------------------------------------
// bf16 NT GEMM: C[m,n] = sum_k A[m,k] * W[n,k] (+ bias)
// BM=128 over m0, BN over n0, K=1024, BK=32, 4 waves in 2x2.
// mode 0: fp32 out[m*D+n], bias[n]
// mode 1: bf16 out[((b*H+h)*S+s)*DK+dk] (split heads), bias[n], *scale
// mode 3: bf16 out[m*4096+n], bias[m]  (V^T: A=Wv rows, W=value rows)
// ---------------------------------------------------------------------------
template<int BN>
__device__ __forceinline__ void gemm_body(
    const u16* __restrict__ A, const u16* __restrict__ W,
    const float* __restrict__ bias, void* __restrict__ outp,
    float scale, int mode, int m0, int n0)
{
    constexpr int NJ = BN / 32;
    __shared__ u16 sA[128 * 32];
    __shared__ u16 sW[BN * 32];

    const int tid  = threadIdx.x;
    const int wave = tid >> 6, lane = tid & 63;
    const int quad = lane >> 4, l16 = lane & 15;
    const int wm = (wave >> 1) * 64;
    const int wn = (wave & 1) * (BN / 2);
    const int lrow = lane >> 2;          // 0..15 within 16-row staging group
    const int lcol = (lane & 3) * 8;     // elem offset within 32-elem row

    f32x4 acc[4][NJ];
    const f32x4 zero = {0.f, 0.f, 0.f, 0.f};
#pragma unroll
    for (int i = 0; i < 4; ++i)
#pragma unroll
        for (int j = 0; j < NJ; ++j) acc[i][j] = zero;

    for (int k0 = 0; k0 < D_; k0 += 32) {
        const int t0 = wave, t1 = wave + 4;
        gload_lds16(A + (size_t)(m0 + t0 * 16 + lrow) * D_ + k0 + lcol, sA + t0 * 512);
        gload_lds16(A + (size_t)(m0 + t1 * 16 + lrow) * D_ + k0 + lcol, sA + t1 * 512);
        if (BN == 128) {
            gload_lds16(W + (size_t)(n0 + t0 * 16 + lrow) * D_ + k0 + lcol, sW + t0 * 512);
            gload_lds16(W + (size_t)(n0 + t1 * 16 + lrow) * D_ + k0 + lcol, sW + t1 * 512);
        } else {
            gload_lds16(W + (size_t)(n0 + wave * 16 + lrow) * D_ + k0 + lcol, sW + wave * 512);
        }
        __syncthreads();

        bf16x8 af[4], bfr[NJ];
#pragma unroll
        for (int i = 0; i < 4; ++i)
            af[i] = *(const bf16x8*)(sA + (wm + i * 16 + l16) * 32 + quad * 8);
#pragma unroll
        for (int j = 0; j < NJ; ++j)
            bfr[j] = *(const bf16x8*)(sW + (wn + j * 16 + l16) * 32 + quad * 8);
#pragma unroll
        for (int i = 0; i < 4; ++i)
#pragma unroll
            for (int j = 0; j < NJ; ++j)
                acc[i][j] = __builtin_amdgcn_mfma_f32_16x16x32_bf16(af[i], bfr[j], acc[i][j], 0, 0, 0);
        __syncthreads();
    }

    // Epilogue. C frag: row = quad*4+reg, col = lane&15
#pragma unroll
    for (int i = 0; i < 4; ++i) {
#pragma unroll
        for (int j = 0; j < NJ; ++j) {
            const int n = n0 + wn + j * 16 + l16;
            if (mode == 3) {
#pragma unroll
                for (int r = 0; r < 4; ++r) {
                    const int mp = m0 + wm + i * 16 + quad * 4 + r;
                    ((u16*)outp)[(size_t)mp * (B_ * S_) + n] = f2bf(acc[i][j][r] + bias[mp]);
                }
            } else {
                const float bn = bias[n];
#pragma unroll
                for (int r = 0; r < 4; ++r) {
                    const int m = m0 + wm + i * 16 + quad * 4 + r;
                    const float v = acc[i][j][r] + bn;
                    if (mode == 0) {
                        ((float*)outp)[(size_t)m * D_ + n] = v;
                    } else {
                        const int b = m >> 11, s = m & (S_ - 1);
                        const int h = n >> 6, dk = n & 63;
                        ((u16*)outp)[(((size_t)(b * H_ + h)) * S_ + s) * DK_ + dk] = f2bf(v * scale);
                    }
                }
            }
        }
    }
}

__global__ __launch_bounds__(256)
void qkv_gemm(const u16* __restrict__ qin, const u16* __restrict__ kin, const u16* __restrict__ vin,
              const u16* __restrict__ wqb, const u16* __restrict__ wkb, const u16* __restrict__ wvb,
              const float* __restrict__ bq, const float* __restrict__ bk, const float* __restrict__ bv,
              u16* __restrict__ Qp, u16* __restrict__ Kp, u16* __restrict__ Vt)
{
    const int z = blockIdx.z;
    if (z == 2) {
        // V^T = Wv . value^T : A = Wv rows (m'=out dim), W = value rows (n'=s)
        gemm_body<128>(wvb, vin, bv, Vt, 1.0f, 3, blockIdx.x * 128, blockIdx.y * 128);
    } else {
        const u16* A = (z == 0) ? qin : kin;
        const u16* W = (z == 0) ? wqb : wkb;
        const float* bias = (z == 0) ? bq : bk;
        u16* outp = (z == 0) ? Qp : Kp;
        // Q pre-scaled by log2(e)/sqrt(DK) so softmax works in exp2 domain
        const float scale = (z == 0) ? 0.18033688011112042f : 1.0f;
        gemm_body<128>(A, W, bias, outp, scale, 1, blockIdx.y * 128, blockIdx.x * 128);
    }
}

__global__ __launch_bounds__(256)
void out_gemm(const u16* __restrict__ Xc, const u16* __restrict__ wob,
              const float* __restrict__ bo, float* __restrict__ out)
{
    gemm_body<64>(Xc, wob, bo, out, 1.0f, 0, blockIdx.y * 128, blockIdx.x * 64);
}

// ---------------------------------------------------------------------------
// MFMA flash attention, S^T orientation + fixed-shift exp2 softmax.
// 4 waves, 128 q-rows/block, 64-key double-buffered tiles, ONE barrier/iter:
// staging into alt buffer is issued right after the top barrier (async DMA in
// flight under QK/softmax/PV); P is wave-private (sQ overlay) so no mid
// barrier. Mask is a precomputed f32 bias folded into the MFMA acc init.
// Vt layout: [h*64+dk][b*2048+s] (row pitch B*S).
// ---------------------------------------------------------------------------
__global__ __launch_bounds__(256)
void attn_mfma(const u16* __restrict__ Qp, const u16* __restrict__ Kp,
               const u16* __restrict__ Vt, const float* __restrict__ mbias,
               u16* __restrict__ Xc)
{
    __shared__ u16 sQ[128 * 64];      // 16 KB; reused as P after preload
    __shared__ u16 sK[2][64 * 64];    // 16 KB double-buffered
    __shared__ u16 sV[2][64 * 64];    // 16 KB double-buffered

    const int tid  = threadIdx.x;
    const int wave = tid >> 6, lane = tid & 63;
    const int quad = lane >> 4, l16 = lane & 15;
    const int qt = blockIdx.x & 15;
    const int bh = blockIdx.x >> 4;
    const int b  = bh >> 4;
    const int h  = bh & 15;
    const int srow = lane >> 3;                  // staging row within 8-row group
    const int scol = ((lane & 7) ^ srow) * 8;    // swizzled source column (u16)
    const int sw7  = l16 & 7;                    // row&7 for fragment reads

    const u16* Qb = Qp + ((size_t)bh * S_ + qt * 128) * DK_;
    const u16* Kb = Kp + (size_t)bh * S_ * DK_;
    const u16* Vb = Vt + ((size_t)h * 64) * (B_ * S_) + b * S_;
    const float* mbf = mbias + b * S_;

    // stage Q tile (128x64) + K/V tile 0, swizzled
#pragma unroll
    for (int t = 0; t < 4; ++t) {
        const int tt = wave + t * 4;
        gload_lds16(Qb + (size_t)(tt * 8 + srow) * DK_ + scol, sQ + tt * 512);
    }
#pragma unroll
    for (int t = 0; t < 2; ++t) {
        const int tt = wave + t * 4;
        gload_lds16(Kb + (size_t)(tt * 8 + srow) * DK_ + scol, &sK[0][tt * 512]);
        gload_lds16(Vb + (size_t)(tt * 8 + srow) * (B_ * S_) + scol, &sV[0][tt * 512]);
    }
    __syncthreads();

    // preload Q as B-frags: B[n=q=l16][k=quad*8+j], per wave q in [w*32, w*32+32)
    bf16x8 qf[2][2];
#pragma unroll
    for (int iq = 0; iq < 2; ++iq)
#pragma unroll
        for (int ks = 0; ks < 2; ++ks) {
            const int row = wave * 32 + iq * 16 + l16;
            const int phys = (ks * 4 + quad) ^ sw7;
            qf[iq][ks] = *(const bf16x8*)(sQ + row * 64 + phys * 8);
        }
    // sQ becomes P after the loop-top barrier of iter 0 (fences qf preload)
    u16* sPw = sQ + wave * 2048;   // this wave's 32x64 P tile

    f32x4 oacc[2][4];              // [im(q)][nd(d)]
    const f32x4 zero = {0.f, 0.f, 0.f, 0.f};
#pragma unroll
    for (int im = 0; im < 2; ++im)
#pragma unroll
        for (int nd = 0; nd < 4; ++nd) oacc[im][nd] = zero;
    f32x4 lsum4[2] = {zero, zero}; // [iq], component = in

    float4 mk4[4];                 // mask bias for current tile (per key row)
#pragma unroll
    for (int in = 0; in < 4; ++in)
        mk4[in] = *(const float4*)(mbf + in * 16 + quad * 4);

    for (int kt = 0; kt < NT_; ++kt) {
        __syncthreads();            // cur buf staged; prev iter's reads done
        const int cur = kt & 1;

        // issue next tile's staging NOW (async, drains at next top barrier)
        if (kt < NT_ - 1) {
            const int alt = cur ^ 1;
#pragma unroll
            for (int t = 0; t < 2; ++t) {
                const int tt = wave + t * 4;
                gload_lds16(Kb + (size_t)((kt + 1) * 64 + tt * 8 + srow) * DK_ + scol, &sK[alt][tt * 512]);
                gload_lds16(Vb + (size_t)(tt * 8 + srow) * (B_ * S_) + (kt + 1) * 64 + scol, &sV[alt][tt * 512]);
            }
        }
        // prefetch next tile's mask bias
        float4 mkn[4];
        const int ktn = (kt < NT_ - 1) ? kt + 1 : kt;
#pragma unroll
        for (int in = 0; in < 4; ++in)
            mkn[in] = *(const float4*)(mbf + ktn * 64 + in * 16 + quad * 4);

        // init S^T acc with mask bias (masked key row -> -1e9 -> exp2 -> 0)
        f32x4 sfr[2][4];
#pragma unroll
        for (int iq = 0; iq < 2; ++iq)
#pragma unroll
            for (int in = 0; in < 4; ++in) {
                sfr[iq][in][0] = mk4[in].x;
                sfr[iq][in][1] = mk4[in].y;
                sfr[iq][in][2] = mk4[in].z;
                sfr[iq][in][3] = mk4[in].w;
            }

        // S^T = K . Q^T  (A = K rows -> m=key, B = Q -> n=q)
#pragma unroll
        for (int in = 0; in < 4; ++in) {
#pragma unroll
            for (int ks = 0; ks < 2; ++ks) {
                const int phys = (ks * 4 + quad) ^ sw7;
                const bf16x8 kf = *(const bf16x8*)(&sK[cur][(in * 16 + l16) * 64 + phys * 8]);
#pragma unroll
                for (int iq = 0; iq < 2; ++iq)
                    sfr[iq][in] = __builtin_amdgcn_mfma_f32_16x16x32_bf16(kf, qf[iq][ks], sfr[iq][in], 0, 0, 0);
            }
        }

        // exp2 (fixed shift), per-lane partial row sums, pack P -> LDS b64
#pragma unroll
        for (int iq = 0; iq < 2; ++iq) {
#pragma unroll
            for (int in = 0; in < 4; ++in) {
                const float p0 = __builtin_amdgcn_exp2f(sfr[iq][in][0]);
                const float p1 = __builtin_amdgcn_exp2f(sfr[iq][in][1]);
                const float p2 = __builtin_amdgcn_exp2f(sfr[iq][in][2]);
                const float p3 = __builtin_amdgcn_exp2f(sfr[iq][in][3]);
                lsum4[iq][in] += (p0 + p1) + (p2 + p3);
                uint2 o;
                o.x = pack_bf16_2(p0, p1);
                o.y = pack_bf16_2(p2, p3);
                // P[q][k]: q=iq*16+l16, k=in*16+quad*4+r ; chunk=(k>>3)^(q&7)
                const int pchunk = (in * 2 + (quad >> 1)) ^ sw7;
                *(uint2*)(sPw + (iq * 16 + l16) * 64 + pchunk * 8 + (quad & 1) * 4) = o;
            }
        }
#pragma unroll
        for (int in = 0; in < 4; ++in) mk4[in] = mkn[in];

        // PV: A = P (m=q, wave-private; lgkmcnt wait auto), B = V^T tile (n=d)
#pragma unroll
        for (int ks = 0; ks < 2; ++ks) {
            bf16x8 pf[2];
#pragma unroll
            for (int im = 0; im < 2; ++im) {
                const int phys = (ks * 4 + quad) ^ sw7;
                pf[im] = *(const bf16x8*)(sPw + (im * 16 + l16) * 64 + phys * 8);
            }
#pragma unroll
            for (int nd = 0; nd < 4; ++nd) {
                const int phys = (ks * 4 + quad) ^ sw7;
                const bf16x8 vf = *(const bf16x8*)(&sV[cur][(nd * 16 + l16) * 64 + phys * 8]);
#pragma unroll
                for (int im = 0; im < 2; ++im)
                    oacc[im][nd] = __builtin_amdgcn_mfma_f32_16x16x32_bf16(pf[im], vf, oacc[im][nd], 0, 0, 0);
            }
        }
    }

    // finalize lsum: in-lane over `in`, then across quads (keys) only
    float lq[2];
#pragma unroll
    for (int iq = 0; iq < 2; ++iq) {
        float v = (lsum4[iq][0] + lsum4[iq][1]) + (lsum4[iq][2] + lsum4[iq][3]);
        v += __shfl_xor(v, 16);
        v += __shfl_xor(v, 32);
        lq[iq] = v;
    }
    // transpose lsum (q in l16) -> O-frag rows (q in quad*4+r) via wave-private LDS
    float* sL = (float*)sPw;
    if (quad == 0) {
        sL[l16] = lq[0];
        sL[16 + l16] = lq[1];
    }
    float linv[2][4];
#pragma unroll
    for (int im = 0; im < 2; ++im)
#pragma unroll
        for (int r = 0; r < 4; ++r)
            linv[im][r] = __builtin_amdgcn_rcpf(sL[im * 16 + quad * 4 + r]);

    // write O (merge-heads) bf16
#pragma unroll
    for (int im = 0; im < 2; ++im)
#pragma unroll
        for (int r = 0; r < 4; ++r) {
            const int s = qt * 128 + wave * 32 + im * 16 + quad * 4 + r;
            const float inv = linv[im][r];
#pragma unroll
            for (int nd = 0; nd < 4; ++nd)
                Xc[((size_t)(b * S_ + s)) * D_ + h * 64 + nd * 16 + l16] =
                    f2bf(oacc[im][nd][r] * inv);
        }
}

// ---------------------------------------------------------------------------
extern "C" void kernel_launch(void* const* d_in, const int* in_sizes, int n_in,
                              void* d_out, int out_size, void* d_ws, size_t ws_size,
                              hipStream_t stream)
{
    (void)in_sizes; (void)n_in; (void)out_size; (void)ws_size;

    const float* query = (const float*)d_in[0];
    const float* key   = (const float*)d_in[1];
    const float* value = (const float*)d_in[2];
    const int*   mask  = (const int*)d_in[3];
    const float* wq    = (const float*)d_in[4];
    const float* bq    = (const float*)d_in[5];
    const float* wk    = (const float*)d_in[6];
    const float* bk    = (const float*)d_in[7];
    const float* wv    = (const float*)d_in[8];
    const float* bv    = (const float*)d_in[9];
    const float* wo    = (const float*)d_in[10];
    const float* bo    = (const float*)d_in[11];

    const size_t NE = (size_t)B_ * S_ * D_;   // 4,194,304
    const size_t WE = (size_t)D_ * D_;        // 1,048,576

    u16* qb  = (u16*)d_ws;      // bf16 inputs
    u16* kb  = qb + NE;
    u16* vb  = kb + NE;
    u16* wqb = vb + NE;         // bf16 weights
    u16* wkb = wqb + WE;
    u16* wvb = wkb + WE;
    u16* wob = wvb + WE;
    u16* Qp  = wob + WE;        // projected heads
    u16* Kp  = Qp + NE;
    u16* Vt  = Kp + NE;         // V transposed: [h*64+dk][b*2048+s]
    float* mbias = (float*)(Vt + NE);   // 4096 f32 mask bias
    u16* Xc  = qb;              // alias: qb is dead after qkv_gemm

    cast_all<<<16400, 256, 0, stream>>>(query, key, value, wq, wk, wv, wo, mask,
                                        qb, kb, vb, wqb, wkb, wvb, wob, mbias);

    qkv_gemm<<<dim3(D_ / 128, (B_ * S_) / 128, 3), 256, 0, stream>>>(
        qb, kb, vb, wqb, wkb, wvb, bq, bk, bv, Qp, Kp, Vt);

    attn_mfma<<<dim3(B_ * H_ * (S_ / 128)), 256, 0, stream>>>(Qp, Kp, Vt, mbias, Xc);

    out_gemm<<<dim3(D_ / 64, (B_ * S_) / 128), 256, 0, stream>>>(Xc, wob, bo, (float*)d_out);
}

// Round 5
// 240.398 us; speedup vs baseline: 7.8778x; 1.0076x over previous
//
#include <hip/hip_runtime.h>
#include <math.h>

#define B_  2
#define S_  2048
#define D_  1024
#define H_  16
#define DK_ 64
#define NT_ (S_ / 64)   // 32 key tiles

typedef unsigned short u16;
typedef unsigned int u32;
typedef __bf16 bf16x8 __attribute__((ext_vector_type(8)));
typedef float f32x4 __attribute__((ext_vector_type(4)));

typedef const __attribute__((address_space(1))) void* gas1_t;
typedef __attribute__((address_space(3))) void* las3_t;

__device__ __forceinline__ void gload_lds16(const void* g, void* l) {
    // async global->LDS, 16B per lane; LDS dst = wave-uniform base + lane*16
    __builtin_amdgcn_global_load_lds((gas1_t)g, (las3_t)l, 16, 0, 0);
}

__device__ __forceinline__ u16 f2bf(float f) {
    union { float f; unsigned u; } v; v.f = f;
    return (u16)((v.u + 0x7fffu + ((v.u >> 16) & 1u)) >> 16);   // RNE
}

// pack two f32 into two bf16 (RNE-ish round-half-up) in one u32: [lo | hi<<16]
__device__ __forceinline__ u32 pack_bf16_2(float lo, float hi) {
    union { float f; u32 u; } a, b;
    a.f = lo; b.f = hi;
    return __builtin_amdgcn_perm(b.u + 0x8000u, a.u + 0x8000u, 0x07060302u);
}

// ---------------------------------------------------------------------------
// Fused fp32 -> bf16 cast over all 7 tensors + mask -> f32 factor (1 / 0)
// + per-batch masked-key count (softmax denominator correction).
// grid = 16384 (tensor) + 16 (mfac) + 2 (count) blocks.
// ---------------------------------------------------------------------------
__global__ __launch_bounds__(256)
void cast_all(const float* __restrict__ q, const float* __restrict__ k,
              const float* __restrict__ v, const float* __restrict__ wq,
              const float* __restrict__ wk, const float* __restrict__ wv,
              const float* __restrict__ wo, const int* __restrict__ mask,
              u16* __restrict__ qb, u16* __restrict__ kb, u16* __restrict__ vb,
              u16* __restrict__ wqb, u16* __restrict__ wkb, u16* __restrict__ wvb,
              u16* __restrict__ wob, float* __restrict__ mfac,
              float* __restrict__ nmaskf)
{
    const int bi = blockIdx.x;
    const int tid = threadIdx.x;
    if (bi >= 16400) {                 // masked-key count for batch b
        const int b = bi - 16400;
        __shared__ int red[256];
        int c = 0;
#pragma unroll
        for (int j = 0; j < 8; ++j)
            c += (mask[b * S_ + tid * 8 + j] == 0) ? 1 : 0;
        red[tid] = c;
        __syncthreads();
        for (int s = 128; s > 0; s >>= 1) {
            if (tid < s) red[tid] += red[tid + s];
            __syncthreads();
        }
        if (tid == 0) nmaskf[b] = (float)red[0];
        return;
    }
    if (bi >= 16384) {                 // mask -> float factor
        const int idx = (bi - 16384) * 256 + tid;
        mfac[idx] = mask[idx] ? 1.0f : 0.0f;
        return;
    }
    const int i = bi * 256 + tid;      // float4 index
    const float* src; u16* dst; int off;
    if (i < 3 * 1048576) {
        const int seg = i >> 20; off = i & 1048575;
        src = (seg == 0) ? q : (seg == 1) ? k : v;
        dst = (seg == 0) ? qb : (seg == 1) ? kb : vb;
    } else {
        const int j = i - 3 * 1048576;
        const int seg = j >> 18; off = j & 262143;
        src = (seg == 0) ? wq : (seg == 1) ? wk : (seg == 2) ? wv : wo;
        dst = (seg == 0) ? wqb : (seg == 1) ? wkb : (seg == 2) ? wvb : wob;
    }
    const float4 val = ((const float4*)src)[off];
    uint2 o;
    o.x = pack_bf16_2(val.x, val.y);
    o.y = pack_bf16_2(val.z, val.w);
    ((uint2*)dst)[off] = o;
}

// ---------------------------------------------------------------------------
// bf16 NT GEMM, BK=64, XOR-swizzled LDS (16B chunks, chunk ^= row&7) so
// fragment ds_read_b128 are conflict-free. 4 waves in 2x2. 16 K-iters.
// mode 0: fp32 out[m*D+n], bias[n]
// mode 1: bf16 out[((b*H+h)*S+s)*DK+dk] (split heads), bias[n], *scale,
//         optionally * rowfac[m]   (K projection: zero masked key rows)
// mode 3: bf16 out[m*4096+n], bias[m], optionally * colfac[n]  (V^T)
// ---------------------------------------------------------------------------
template<int BN>
__device__ __forceinline__ void gemm_body(
    const u16* __restrict__ A, const u16* __restrict__ W,
    const float* __restrict__ bias, void* __restrict__ outp,
    float scale, int mode, int m0, int n0,
    const float* __restrict__ rowfac, const float* __restrict__ colfac)
{
    constexpr int NJ = BN / 32;
    __shared__ u16 sA[128 * 64];      // 16 KB
    __shared__ u16 sW[BN * 64];       // 16 or 8 KB

    const int tid  = threadIdx.x;
    const int wave = tid >> 6, lane = tid & 63;
    const int quad = lane >> 4, l16 = lane & 15;
    const int wm = (wave >> 1) * 64;
    const int wn = (wave & 1) * (BN / 2);
    const int srow = lane >> 3;                 // row within 8-row staging group
    const int scol = ((lane & 7) ^ srow) * 8;   // swizzled source column (u16)
    const int sw7  = l16 & 7;

    f32x4 acc[4][NJ];
    const f32x4 zero = {0.f, 0.f, 0.f, 0.f};
#pragma unroll
    for (int i = 0; i < 4; ++i)
#pragma unroll
        for (int j = 0; j < NJ; ++j) acc[i][j] = zero;

    const u16* ast = A + (size_t)(m0 + wave * 8 + srow) * D_ + scol;
    const u16* wst = W + (size_t)(n0 + wave * 8 + srow) * D_ + scol;

    for (int k0 = 0; k0 < D_; k0 += 64) {
#pragma unroll
        for (int t = 0; t < 4; ++t)
            gload_lds16(ast + (size_t)t * 32 * D_ + k0, sA + (wave + t * 4) * 512);
        if (BN == 128) {
#pragma unroll
            for (int t = 0; t < 4; ++t)
                gload_lds16(wst + (size_t)t * 32 * D_ + k0, sW + (wave + t * 4) * 512);
        } else {
#pragma unroll
            for (int t = 0; t < 2; ++t)
                gload_lds16(wst + (size_t)t * 32 * D_ + k0, sW + (wave + t * 4) * 512);
        }
        __syncthreads();

#pragma unroll
        for (int kh = 0; kh < 2; ++kh) {
            const int phys = ((kh * 4 + quad) ^ sw7) * 8;
            bf16x8 af[4], bfr[NJ];
#pragma unroll
            for (int i = 0; i < 4; ++i)
                af[i] = *(const bf16x8*)(sA + (wm + i * 16 + l16) * 64 + phys);
#pragma unroll
            for (int j = 0; j < NJ; ++j)
                bfr[j] = *(const bf16x8*)(sW + (wn + j * 16 + l16) * 64 + phys);
#pragma unroll
            for (int i = 0; i < 4; ++i)
#pragma unroll
                for (int j = 0; j < NJ; ++j)
                    acc[i][j] = __builtin_amdgcn_mfma_f32_16x16x32_bf16(af[i], bfr[j], acc[i][j], 0, 0, 0);
        }
        __syncthreads();
    }

    // Epilogue. C frag: row = quad*4+reg, col = lane&15
#pragma unroll
    for (int i = 0; i < 4; ++i) {
        float rf4[4];
        if (mode == 1 && rowfac) {
#pragma unroll
            for (int r = 0; r < 4; ++r)
                rf4[r] = rowfac[m0 + wm + i * 16 + quad * 4 + r];
        }
#pragma unroll
        for (int j = 0; j < NJ; ++j) {
            const int n = n0 + wn + j * 16 + l16;
            if (mode == 3) {
                const float cf = colfac ? colfac[n] : 1.0f;
#pragma unroll
                for (int r = 0; r < 4; ++r) {
                    const int mp = m0 + wm + i * 16 + quad * 4 + r;
                    ((u16*)outp)[(size_t)mp * (B_ * S_) + n] = f2bf((acc[i][j][r] + bias[mp]) * cf);
                }
            } else {
                const float bn = bias[n];
#pragma unroll
                for (int r = 0; r < 4; ++r) {
                    const int m = m0 + wm + i * 16 + quad * 4 + r;
                    float v = acc[i][j][r] + bn;
                    if (mode == 0) {
                        ((float*)outp)[(size_t)m * D_ + n] = v;
                    } else {
                        v *= scale;
                        if (rowfac) v *= rf4[r];
                        const int b = m >> 11, s = m & (S_ - 1);
                        const int h = n >> 6, dk = n & 63;
                        ((u16*)outp)[(((size_t)(b * H_ + h)) * S_ + s) * DK_ + dk] = f2bf(v);
                    }
                }
            }
        }
    }
}

__global__ __launch_bounds__(256)
void qkv_gemm(const u16* __restrict__ qin, const u16* __restrict__ kin, const u16* __restrict__ vin,
              const u16* __restrict__ wqb, const u16* __restrict__ wkb, const u16* __restrict__ wvb,
              const float* __restrict__ bq, const float* __restrict__ bk, const float* __restrict__ bv,
              u16* __restrict__ Qp, u16* __restrict__ Kp, u16* __restrict__ Vt,
              const float* __restrict__ mfac)
{
    const int z = blockIdx.z;
    if (z == 2) {
        // V^T = Wv . value^T ; zero masked key columns via colfac
        gemm_body<128>(wvb, vin, bv, Vt, 1.0f, 3, blockIdx.x * 128, blockIdx.y * 128,
                       nullptr, mfac);
    } else {
        const u16* A = (z == 0) ? qin : kin;
        const u16* W = (z == 0) ? wqb : wkb;
        const float* bias = (z == 0) ? bq : bk;
        u16* outp = (z == 0) ? Qp : Kp;
        // Q pre-scaled by log2(e)/sqrt(DK); K rows zeroed where masked
        const float scale = (z == 0) ? 0.18033688011112042f : 1.0f;
        const float* rf = (z == 1) ? mfac : nullptr;
        gemm_body<128>(A, W, bias, outp, scale, 1, blockIdx.y * 128, blockIdx.x * 128,
                       rf, nullptr);
    }
}

__global__ __launch_bounds__(256)
void out_gemm(const u16* __restrict__ Xc, const u16* __restrict__ wob,
              const float* __restrict__ bo, float* __restrict__ out)
{
    gemm_body<64>(Xc, wob, bo, out, 1.0f, 0, blockIdx.y * 128, blockIdx.x * 64,
                  nullptr, nullptr);
}

// ---------------------------------------------------------------------------
// MFMA flash attention, S^T orientation, fixed-shift exp2 softmax, maskless
// (masked keys pre-zeroed in K and V^T; denominator corrected by nmaskf[b]).
// lsum computed as P x ones via MFMA -> lands in C-layout (row=q), no
// transpose needed. One barrier per k-tile; K/V double-buffered async DMA.
// ---------------------------------------------------------------------------
__global__ __launch_bounds__(256)
void attn_mfma(const u16* __restrict__ Qp, const u16* __restrict__ Kp,
               const u16* __restrict__ Vt, const float* __restrict__ nmaskf,
               u16* __restrict__ Xc)
{
    __shared__ u16 sQ[128 * 64];      // 16 KB; reused as P after preload
    __shared__ u16 sK[2][64 * 64];    // 16 KB double-buffered
    __shared__ u16 sV[2][64 * 64];    // 16 KB double-buffered

    const int tid  = threadIdx.x;
    const int wave = tid >> 6, lane = tid & 63;
    const int quad = lane >> 4, l16 = lane & 15;
    const int qt = blockIdx.x & 15;
    const int bh = blockIdx.x >> 4;
    const int b  = bh >> 4;
    const int h  = bh & 15;
    const int srow = lane >> 3;                  // staging row within 8-row group
    const int scol = ((lane & 7) ^ srow) * 8;    // swizzled source column (u16)
    const int sw7  = l16 & 7;                    // row&7 for fragment reads

    const u16* Qb = Qp + ((size_t)bh * S_ + qt * 128) * DK_;
    const u16* Kb = Kp + (size_t)bh * S_ * DK_;
    const u16* Vb = Vt + ((size_t)h * 64) * (B_ * S_) + b * S_;

    // stage Q tile (128x64) + K/V tile 0, swizzled
#pragma unroll
    for (int t = 0; t < 4; ++t)
        gload_lds16(Qb + (size_t)((wave + t * 4) * 8 + srow) * DK_ + scol,
                    sQ + (wave + t * 4) * 512);
#pragma unroll
    for (int t = 0; t < 2; ++t) {
        const int tt = wave + t * 4;
        gload_lds16(Kb + (size_t)(tt * 8 + srow) * DK_ + scol, &sK[0][tt * 512]);
        gload_lds16(Vb + (size_t)(tt * 8 + srow) * (B_ * S_) + scol, &sV[0][tt * 512]);
    }
    __syncthreads();

    // preload Q as B-frags: B[n=q=l16][k=quad*8+j], per wave q in [w*32, w*32+32)
    bf16x8 qf[2][2];
#pragma unroll
    for (int iq = 0; iq < 2; ++iq)
#pragma unroll
        for (int ks = 0; ks < 2; ++ks) {
            const int row = wave * 32 + iq * 16 + l16;
            const int phys = (ks * 4 + quad) ^ sw7;
            qf[iq][ks] = *(const bf16x8*)(sQ + row * 64 + phys * 8);
        }
    // sQ becomes P after the loop-top barrier of iter 0 (fences qf preload)
    u16* sPw = sQ + wave * 2048;   // this wave's 32x64 P tile

    bf16x8 vones;
#pragma unroll
    for (int j = 0; j < 8; ++j) vones[j] = (__bf16)1.0f;

    f32x4 oacc[2][4];              // [im(q)][nd(d)]
    const f32x4 zero = {0.f, 0.f, 0.f, 0.f};
#pragma unroll
    for (int im = 0; im < 2; ++im)
#pragma unroll
        for (int nd = 0; nd < 4; ++nd) oacc[im][nd] = zero;
    f32x4 lfrag[2] = {zero, zero}; // lsum in C-layout: row q = quad*4+r

    // incremental staging pointers for tile kt+1
    const u16* kpre = Kb + (size_t)64 * DK_ + (size_t)(wave * 8 + srow) * DK_ + scol;
    const u16* vpre = Vb + 64 + (size_t)(wave * 8 + srow) * (B_ * S_) + scol;

    for (int kt = 0; kt < NT_; ++kt) {
        __syncthreads();            // cur buf staged; prev iter's reads done
        const int cur = kt & 1;

        // issue next tile's staging NOW (async, drains at next top barrier)
        if (kt < NT_ - 1) {
            u16* kdst = &sK[cur ^ 1][wave * 512];
            u16* vdst = &sV[cur ^ 1][wave * 512];
            gload_lds16(kpre, kdst);
            gload_lds16(kpre + (size_t)32 * DK_, kdst + 4 * 512);
            gload_lds16(vpre, vdst);
            gload_lds16(vpre + (size_t)32 * (B_ * S_), vdst + 4 * 512);
            kpre += (size_t)64 * DK_;
            vpre += 64;
        }

        // S^T = K . Q^T  (A = K rows -> m=key, B = Q -> n=q), zero-init chain
        f32x4 sfr[2][4];
#pragma unroll
        for (int in = 0; in < 4; ++in) {
            const int p0 = (quad ^ sw7) * 8;
            const int p1 = ((4 + quad) ^ sw7) * 8;
            const bf16x8 kf0 = *(const bf16x8*)(&sK[cur][(in * 16 + l16) * 64 + p0]);
            const bf16x8 kf1 = *(const bf16x8*)(&sK[cur][(in * 16 + l16) * 64 + p1]);
#pragma unroll
            for (int iq = 0; iq < 2; ++iq) {
                f32x4 t = __builtin_amdgcn_mfma_f32_16x16x32_bf16(kf0, qf[iq][0], zero, 0, 0, 0);
                sfr[iq][in] = __builtin_amdgcn_mfma_f32_16x16x32_bf16(kf1, qf[iq][1], t, 0, 0, 0);
            }
        }

        // exp2 (fixed shift), pack P -> LDS b64 (swizzled)
#pragma unroll
        for (int iq = 0; iq < 2; ++iq) {
#pragma unroll
            for (int in = 0; in < 4; ++in) {
                const float p0 = __builtin_amdgcn_exp2f(sfr[iq][in][0]);
                const float p1 = __builtin_amdgcn_exp2f(sfr[iq][in][1]);
                const float p2 = __builtin_amdgcn_exp2f(sfr[iq][in][2]);
                const float p3 = __builtin_amdgcn_exp2f(sfr[iq][in][3]);
                uint2 o;
                o.x = pack_bf16_2(p0, p1);
                o.y = pack_bf16_2(p2, p3);
                // P[q][k]: q=iq*16+l16, k=in*16+quad*4+r ; chunk=(k>>3)^(q&7)
                const int pchunk = (in * 2 + (quad >> 1)) ^ sw7;
                *(uint2*)(sPw + (iq * 16 + l16) * 64 + pchunk * 8 + (quad & 1) * 4) = o;
            }
        }

        // PV + lsum: A = P (m=q, wave-private), B = V^T tile (n=d) / ones
#pragma unroll
        for (int ks = 0; ks < 2; ++ks) {
            const int phys = ((ks * 4 + quad) ^ sw7) * 8;
            bf16x8 pf[2];
#pragma unroll
            for (int im = 0; im < 2; ++im)
                pf[im] = *(const bf16x8*)(sPw + (im * 16 + l16) * 64 + phys);
#pragma unroll
            for (int im = 0; im < 2; ++im)
                lfrag[im] = __builtin_amdgcn_mfma_f32_16x16x32_bf16(pf[im], vones, lfrag[im], 0, 0, 0);
#pragma unroll
            for (int nd = 0; nd < 4; ++nd) {
                const bf16x8 vf = *(const bf16x8*)(&sV[cur][(nd * 16 + l16) * 64 + phys]);
#pragma unroll
                for (int im = 0; im < 2; ++im)
                    oacc[im][nd] = __builtin_amdgcn_mfma_f32_16x16x32_bf16(pf[im], vf, oacc[im][nd], 0, 0, 0);
            }
        }
    }

    // denominator: lfrag rows already hold full row sums (all 16 cols equal);
    // subtract masked-key count (their P contributions are exp2(0)=1 each).
    const float nm = nmaskf[b];
    float linv[2][4];
#pragma unroll
    for (int im = 0; im < 2; ++im)
#pragma unroll
        for (int r = 0; r < 4; ++r)
            linv[im][r] = __builtin_amdgcn_rcpf(lfrag[im][r] - nm);

    // write O (merge-heads) bf16
#pragma unroll
    for (int im = 0; im < 2; ++im)
#pragma unroll
        for (int r = 0; r < 4; ++r) {
            const int s = qt * 128 + wave * 32 + im * 16 + quad * 4 + r;
            const float inv = linv[im][r];
#pragma unroll
            for (int nd = 0; nd < 4; ++nd)
                Xc[((size_t)(b * S_ + s)) * D_ + h * 64 + nd * 16 + l16] =
                    f2bf(oacc[im][nd][r] * inv);
        }
}

// ---------------------------------------------------------------------------
extern "C" void kernel_launch(void* const* d_in, const int* in_sizes, int n_in,
                              void* d_out, int out_size, void* d_ws, size_t ws_size,
                              hipStream_t stream)
{
    (void)in_sizes; (void)n_in; (void)out_size; (void)ws_size;

    const float* query = (const float*)d_in[0];
    const float* key   = (const float*)d_in[1];
    const float* value = (const float*)d_in[2];
    const int*   mask  = (const int*)d_in[3];
    const float* wq    = (const float*)d_in[4];
    const float* bq    = (const float*)d_in[5];
    const float* wk    = (const float*)d_in[6];
    const float* bk    = (const float*)d_in[7];
    const float* wv    = (const float*)d_in[8];
    const float* bv    = (const float*)d_in[9];
    const float* wo    = (const float*)d_in[10];
    const float* bo    = (const float*)d_in[11];

    const size_t NE = (size_t)B_ * S_ * D_;   // 4,194,304
    const size_t WE = (size_t)D_ * D_;        // 1,048,576

    u16* qb  = (u16*)d_ws;      // bf16 inputs
    u16* kb  = qb + NE;
    u16* vb  = kb + NE;
    u16* wqb = vb + NE;         // bf16 weights
    u16* wkb = wqb + WE;
    u16* wvb = wkb + WE;
    u16* wob = wvb + WE;
    u16* Qp  = wob + WE;        // projected heads
    u16* Kp  = Qp + NE;
    u16* Vt  = Kp + NE;         // V transposed: [h*64+dk][b*2048+s]
    float* mfac   = (float*)(Vt + NE);   // 4096 f32 mask factors (1/0)
    float* nmaskf = mfac + 4096;         // 2 f32 masked-key counts
    u16* Xc  = qb;              // alias: qb is dead after qkv_gemm

    cast_all<<<16402, 256, 0, stream>>>(query, key, value, wq, wk, wv, wo, mask,
                                        qb, kb, vb, wqb, wkb, wvb, wob, mfac, nmaskf);

    qkv_gemm<<<dim3(D_ / 128, (B_ * S_) / 128, 3), 256, 0, stream>>>(
        qb, kb, vb, wqb, wkb, wvb, bq, bk, bv, Qp, Kp, Vt, mfac);

    attn_mfma<<<dim3(B_ * H_ * (S_ / 128)), 256, 0, stream>>>(Qp, Kp, Vt, nmaskf, Xc);

    out_gemm<<<dim3(D_ / 64, (B_ * S_) / 128), 256, 0, stream>>>(Xc, wob, bo, (float*)d_out);
}